// Round 2
// baseline (992.547 us; speedup 1.0000x reference)
//
#include <hip/hip_runtime.h>
#include <hip/hip_bf16.h>

#define NSP 4096      // D*H*W
#define CH 256
#define NB 2
#define NG 8
#define CPG 32        // channels per group
#define NHD 4         // heads
#define HDIM 64       // head dim

typedef unsigned short u16;
typedef unsigned int u32;

__device__ __forceinline__ float bf2f(u16 u) {
    union { u32 i; float f; } v; v.i = ((u32)u) << 16; return v.f;
}
__device__ __forceinline__ u16 f2bf(float f) {
    u32 i = __float_as_uint(f);
    u32 r = (i + 0x7FFFu + ((i >> 16) & 1u)) >> 16;   // round-nearest-even
    return (u16)r;
}
// stage 8 bf16 (16B aligned) from global -> 8 contiguous fp32 in LDS
__device__ __forceinline__ void stage8(const u16* __restrict__ g, float* __restrict__ s) {
    uint4 u = *(const uint4*)g;
    s[0] = bf2f((u16)(u.x & 0xFFFFu)); s[1] = bf2f((u16)(u.x >> 16));
    s[2] = bf2f((u16)(u.y & 0xFFFFu)); s[3] = bf2f((u16)(u.y >> 16));
    s[4] = bf2f((u16)(u.z & 0xFFFFu)); s[5] = bf2f((u16)(u.z >> 16));
    s[6] = bf2f((u16)(u.w & 0xFFFFu)); s[7] = bf2f((u16)(u.w >> 16));
}

// ---------------- GroupNorm stats: one block per (b,g), fp32 input ----------------
__global__ __launch_bounds__(256) void gn_stats(const float* __restrict__ x,
                                                float* __restrict__ stats) {
    int bg = blockIdx.x;                       // 0..15 ; contiguous 32x4096 chunk
    const float* p = x + (size_t)bg * (CPG * NSP);
    float s = 0.f, ss = 0.f;
    const int nv = (CPG * NSP) / 4;            // float4 loads
    for (int i = threadIdx.x; i < nv; i += 256) {
        float4 u = ((const float4*)p)[i];
        s += u.x + u.y + u.z + u.w;
        ss += u.x * u.x + u.y * u.y + u.z * u.z + u.w * u.w;
    }
    __shared__ float rs[256], rq[256];
    rs[threadIdx.x] = s; rq[threadIdx.x] = ss;
    __syncthreads();
    for (int st = 128; st > 0; st >>= 1) {
        if (threadIdx.x < st) { rs[threadIdx.x] += rs[threadIdx.x + st];
                                rq[threadIdx.x] += rq[threadIdx.x + st]; }
        __syncthreads();
    }
    if (threadIdx.x == 0) {
        const float cnt = (float)(CPG * NSP);
        float mean = rs[0] / cnt;
        float var  = rq[0] / cnt - mean * mean;
        stats[bg * 2]     = mean;
        stats[bg * 2 + 1] = rsqrtf(var + 1e-5f);
    }
}

// ---------------- GroupNorm apply: fp32 in, bf16 out ----------------
__global__ __launch_bounds__(256) void gn_apply(const float* __restrict__ x,
                                                const float* __restrict__ stats,
                                                const float* __restrict__ w,
                                                const float* __restrict__ b,
                                                u16* __restrict__ xn) {
    int bc = blockIdx.x;                       // 0..511
    int c  = bc & (CH - 1);
    int bg = (bc / CH) * NG + (c / CPG);
    float mean = stats[bg * 2], rstd = stats[bg * 2 + 1];
    float wf = w[c] * rstd;
    float bv = b[c] - mean * wf;
    const float* px = x + (size_t)bc * NSP;
    u16* po = xn + (size_t)bc * NSP;
    for (int i = threadIdx.x; i < NSP / 4; i += 256) {
        float4 u = ((const float4*)px)[i];
        ushort4 o;
        o.x = f2bf(u.x * wf + bv);
        o.y = f2bf(u.y * wf + bv);
        o.z = f2bf(u.z * wf + bv);
        o.w = f2bf(u.w * wf + bv);
        ((ushort4*)po)[i] = o;
    }
}

// ------- tiled GEMM: Y[b][m][n] = sum_c A[m][c]*X[b][c][n] + bias[m] (+res) -------
// A,bias fp32; X bf16. out_f32: Y fp32 with fp32 residual; else Y bf16.
// K = CH = 256 fixed. 64x64 block tile, 256 threads, 4x4 per thread.
__global__ __launch_bounds__(256) void gemm_bias(const float* __restrict__ A,
                                                 const float* __restrict__ bias,
                                                 const u16* __restrict__ X,
                                                 const float* __restrict__ res,
                                                 void* __restrict__ Yv, int M,
                                                 int out_f32) {
    __shared__ float As[16][72];
    __shared__ float Xs[16][72];
    const int n0 = blockIdx.x * 64;
    const int m0 = blockIdx.y * 64;
    const int b  = blockIdx.z;
    const u16* Xb = X + (size_t)b * CH * NSP;
    const int t  = threadIdx.x;
    const int tx = t & 15, ty = t >> 4;
    const int am = t >> 2, ak = (t & 3) * 4;   // A tile: 64 m x 16 k
    const int xk = t >> 4, xn4 = (t & 15) * 4; // X tile: 16 k x 64 n
    float acc[4][4] = {};
    for (int k0 = 0; k0 < CH; k0 += 16) {
        float4 av = *(const float4*)(A + (size_t)(m0 + am) * CH + k0 + ak);
        As[ak + 0][am] = av.x;
        As[ak + 1][am] = av.y;
        As[ak + 2][am] = av.z;
        As[ak + 3][am] = av.w;
        ushort4 xv = *(const ushort4*)(Xb + (size_t)(k0 + xk) * NSP + n0 + xn4);
        Xs[xk][xn4 + 0] = bf2f(xv.x);
        Xs[xk][xn4 + 1] = bf2f(xv.y);
        Xs[xk][xn4 + 2] = bf2f(xv.z);
        Xs[xk][xn4 + 3] = bf2f(xv.w);
        __syncthreads();
#pragma unroll
        for (int kk = 0; kk < 16; ++kk) {
            float4 a4 = *(const float4*)&As[kk][ty * 4];
            float4 x4 = *(const float4*)&Xs[kk][tx * 4];
            float aa[4] = {a4.x, a4.y, a4.z, a4.w};
            float xx[4] = {x4.x, x4.y, x4.z, x4.w};
#pragma unroll
            for (int i = 0; i < 4; ++i)
#pragma unroll
                for (int j = 0; j < 4; ++j) acc[i][j] += aa[i] * xx[j];
        }
        __syncthreads();
    }
#pragma unroll
    for (int i = 0; i < 4; ++i) {
        int r = m0 + ty * 4 + i;
        float bvv = bias[r];
        float v[4];
#pragma unroll
        for (int j = 0; j < 4; ++j) v[j] = acc[i][j] + bvv;
        if (out_f32) {
            const float* rp = res + (size_t)b * CH * NSP + (size_t)r * NSP + n0 + tx * 4;
            float4 rv = *(const float4*)rp;
            float4 ov;
            ov.x = v[0] + rv.x; ov.y = v[1] + rv.y;
            ov.z = v[2] + rv.z; ov.w = v[3] + rv.w;
            float* Yb = (float*)Yv + (size_t)b * M * NSP;
            *(float4*)(Yb + (size_t)r * NSP + n0 + tx * 4) = ov;
        } else {
            ushort4 ov; ov.x = f2bf(v[0]); ov.y = f2bf(v[1]);
            ov.z = f2bf(v[2]); ov.w = f2bf(v[3]);
            u16* Yb = (u16*)Yv + (size_t)b * M * NSP;
            *(ushort4*)(Yb + (size_t)r * NSP + n0 + tx * 4) = ov;
        }
    }
}

// ---------------- flash attention: one block per (b, h, 64-query tile) ----------------
// qkv layout: [B][3*CH][NSP] bf16. Q tile [c][q], K/V tile [c][k] share one buffer.
__global__ __launch_bounds__(256) void attn_kernel(const u16* __restrict__ qkv,
                                                   u16* __restrict__ ao) {
    __shared__ float Qs[64][68];
    __shared__ float KVs[64][68];
    __shared__ float Ss[64][68];
    __shared__ float mrow[64], lrow[64], arow[64];
    const int n0 = blockIdx.x * 64;
    const int h  = blockIdx.y;
    const int b  = blockIdx.z;
    const u16* qb = qkv + ((size_t)b * 3 * CH + h * HDIM) * NSP;
    const u16* kb = qb + (size_t)CH * NSP;
    const u16* vb = kb + (size_t)CH * NSP;
    const int t  = threadIdx.x;
    const int tx = t & 15, ty = t >> 4;
    const int lc = t >> 2, lq = (t & 3) * 16;  // staging: 16 elems/thread
    // stage Q tile
    {
        const u16* src = qb + (size_t)lc * NSP + n0 + lq;
        stage8(src,     &Qs[lc][lq]);
        stage8(src + 8, &Qs[lc][lq + 8]);
    }
    if (t < 64) { mrow[t] = -1e30f; lrow[t] = 0.f; }
    float O[4][4] = {};
    for (int kt = 0; kt < 64; ++kt) {
        const int k0 = kt * 64;
        // stage K tile
        {
            const u16* src = kb + (size_t)lc * NSP + k0 + lq;
            stage8(src,     &KVs[lc][lq]);
            stage8(src + 8, &KVs[lc][lq + 8]);
        }
        __syncthreads();
        // S[q][k] = scale * sum_c Q[c][q] * K[c][k]
        float sacc[4][4] = {};
#pragma unroll 8
        for (int cc = 0; cc < 64; ++cc) {
            float4 a4 = *(const float4*)&Qs[cc][ty * 4];
            float4 b4 = *(const float4*)&KVs[cc][tx * 4];
            float aa[4] = {a4.x, a4.y, a4.z, a4.w};
            float bb[4] = {b4.x, b4.y, b4.z, b4.w};
#pragma unroll
            for (int i = 0; i < 4; ++i)
#pragma unroll
                for (int j = 0; j < 4; ++j) sacc[i][j] += aa[i] * bb[j];
        }
#pragma unroll
        for (int i = 0; i < 4; ++i)
#pragma unroll
            for (int j = 0; j < 4; ++j)
                Ss[ty * 4 + i][tx * 4 + j] = sacc[i][j] * 0.125f;
        __syncthreads();
        // stage V tile (K no longer needed) + online softmax in parallel
        {
            const u16* src = vb + (size_t)lc * NSP + k0 + lq;
            stage8(src,     &KVs[lc][lq]);
            stage8(src + 8, &KVs[lc][lq + 8]);
        }
        if (t < 64) {
            float mprev = mrow[t];
            float mx = mprev;
#pragma unroll 8
            for (int k = 0; k < 64; ++k) mx = fmaxf(mx, Ss[t][k]);
            float al = __expf(mprev - mx);
            float sum = 0.f;
#pragma unroll 8
            for (int k = 0; k < 64; ++k) {
                float p = __expf(Ss[t][k] - mx);
                Ss[t][k] = p;
                sum += p;
            }
            mrow[t] = mx;
            lrow[t] = lrow[t] * al + sum;
            arow[t] = al;
        }
        __syncthreads();
        // O[c][q] = O*alpha[q] + sum_k V[c][k] * P[q][k]
        float al[4];
#pragma unroll
        for (int j = 0; j < 4; ++j) al[j] = arow[tx * 4 + j];
#pragma unroll
        for (int i = 0; i < 4; ++i)
#pragma unroll
            for (int j = 0; j < 4; ++j) O[i][j] *= al[j];
        for (int kk = 0; kk < 64; kk += 4) {
            float4 v4[4], s4[4];
#pragma unroll
            for (int i = 0; i < 4; ++i) v4[i] = *(const float4*)&KVs[ty * 4 + i][kk];
#pragma unroll
            for (int j = 0; j < 4; ++j) s4[j] = *(const float4*)&Ss[tx * 4 + j][kk];
#pragma unroll
            for (int i = 0; i < 4; ++i)
#pragma unroll
                for (int j = 0; j < 4; ++j)
                    O[i][j] += v4[i].x * s4[j].x + v4[i].y * s4[j].y +
                               v4[i].z * s4[j].z + v4[i].w * s4[j].w;
        }
        __syncthreads();
    }
    float linv[4];
#pragma unroll
    for (int j = 0; j < 4; ++j) linv[j] = 1.f / lrow[tx * 4 + j];
    u16* aob = ao + ((size_t)b * CH + h * HDIM) * NSP;
#pragma unroll
    for (int i = 0; i < 4; ++i) {
        int c = ty * 4 + i;
        ushort4 ov;
        ov.x = f2bf(O[i][0] * linv[0]);
        ov.y = f2bf(O[i][1] * linv[1]);
        ov.z = f2bf(O[i][2] * linv[2]);
        ov.w = f2bf(O[i][3] * linv[3]);
        *(ushort4*)(aob + (size_t)c * NSP + n0 + tx * 4) = ov;
    }
}

extern "C" void kernel_launch(void* const* d_in, const int* in_sizes, int n_in,
                              void* d_out, int out_size, void* d_ws, size_t ws_size,
                              hipStream_t stream) {
    const float* x      = (const float*)d_in[0];
    const float* norm_w = (const float*)d_in[1];
    const float* norm_b = (const float*)d_in[2];
    const float* qkv_w  = (const float*)d_in[3];
    const float* qkv_b  = (const float*)d_in[4];
    const float* proj_w = (const float*)d_in[5];
    const float* proj_b = (const float*)d_in[6];
    float* out = (float*)d_out;

    char* w = (char*)d_ws;
    float* stats = (float*)w;                                   // 128 B
    u16* xn  = (u16*)(w + 1024);                                // 4 MB bf16
    u16* qkv = (u16*)(w + 1024 + 4194304);                      // 12 MB bf16
    u16* ao  = (u16*)(w + 1024 + 4194304 + 12582912);           // 4 MB bf16

    gn_stats<<<dim3(NB * NG), 256, 0, stream>>>(x, stats);
    gn_apply<<<dim3(NB * CH), 256, 0, stream>>>(x, stats, norm_w, norm_b, xn);
    gemm_bias<<<dim3(NSP / 64, (3 * CH) / 64, NB), 256, 0, stream>>>(
        qkv_w, qkv_b, xn, nullptr, (void*)qkv, 3 * CH, 0);
    attn_kernel<<<dim3(NSP / 64, NHD, NB), 256, 0, stream>>>(qkv, ao);
    gemm_bias<<<dim3(NSP / 64, CH / 64, NB), 256, 0, stream>>>(
        proj_w, proj_b, ao, x, (void*)out, CH, 1);
}

// Round 3
// 296.912 us; speedup vs baseline: 3.3429x; 3.3429x over previous
//
#include <hip/hip_runtime.h>
#include <hip/hip_bf16.h>

#define NSP 4096      // D*H*W
#define CH 256
#define NB 2
#define NG 8
#define CPG 32        // channels per group
#define NHD 4         // heads
#define HDIM 64       // head dim

typedef unsigned short u16;
typedef unsigned int u32;
typedef __attribute__((ext_vector_type(8))) short bf16x8;
typedef __attribute__((ext_vector_type(4))) float f32x4;

__device__ __forceinline__ float bf2f(u16 u) {
    union { u32 i; float f; } v; v.i = ((u32)u) << 16; return v.f;
}
__device__ __forceinline__ u16 f2bf(float f) {
    u32 i = __float_as_uint(f);
    u32 r = (i + 0x7FFFu + ((i >> 16) & 1u)) >> 16;   // round-nearest-even
    return (u16)r;
}

// ---------------- GroupNorm stats: one block per (b,g), fp32 input ----------------
__global__ __launch_bounds__(256) void gn_stats(const float* __restrict__ x,
                                                float* __restrict__ stats) {
    int bg = blockIdx.x;                       // 0..15 ; contiguous 32x4096 chunk
    const float* p = x + (size_t)bg * (CPG * NSP);
    float s = 0.f, ss = 0.f;
    const int nv = (CPG * NSP) / 4;            // float4 loads
    for (int i = threadIdx.x; i < nv; i += 256) {
        float4 u = ((const float4*)p)[i];
        s += u.x + u.y + u.z + u.w;
        ss += u.x * u.x + u.y * u.y + u.z * u.z + u.w * u.w;
    }
    __shared__ float rs[256], rq[256];
    rs[threadIdx.x] = s; rq[threadIdx.x] = ss;
    __syncthreads();
    for (int st = 128; st > 0; st >>= 1) {
        if (threadIdx.x < st) { rs[threadIdx.x] += rs[threadIdx.x + st];
                                rq[threadIdx.x] += rq[threadIdx.x + st]; }
        __syncthreads();
    }
    if (threadIdx.x == 0) {
        const float cnt = (float)(CPG * NSP);
        float mean = rs[0] / cnt;
        float var  = rq[0] / cnt - mean * mean;
        stats[bg * 2]     = mean;
        stats[bg * 2 + 1] = rsqrtf(var + 1e-5f);
    }
}

// ---------------- GroupNorm apply: fp32 in, bf16 out ----------------
__global__ __launch_bounds__(256) void gn_apply(const float* __restrict__ x,
                                                const float* __restrict__ stats,
                                                const float* __restrict__ w,
                                                const float* __restrict__ b,
                                                u16* __restrict__ xn) {
    int bc = blockIdx.x;                       // 0..511
    int c  = bc & (CH - 1);
    int bg = (bc / CH) * NG + (c / CPG);
    float mean = stats[bg * 2], rstd = stats[bg * 2 + 1];
    float wf = w[c] * rstd;
    float bv = b[c] - mean * wf;
    const float* px = x + (size_t)bc * NSP;
    u16* po = xn + (size_t)bc * NSP;
    for (int i = threadIdx.x; i < NSP / 4; i += 256) {
        float4 u = ((const float4*)px)[i];
        ushort4 o;
        o.x = f2bf(u.x * wf + bv);
        o.y = f2bf(u.y * wf + bv);
        o.z = f2bf(u.z * wf + bv);
        o.w = f2bf(u.w * wf + bv);
        ((ushort4*)po)[i] = o;
    }
}

// ------- tiled GEMM: Y[b][m][n] = sum_c A[m][c]*X[b][c][n] + bias[m] (+res) -------
// A,bias fp32; X bf16. out_f32: Y fp32 with fp32 residual; else Y bf16.
__global__ __launch_bounds__(256) void gemm_bias(const float* __restrict__ A,
                                                 const float* __restrict__ bias,
                                                 const u16* __restrict__ X,
                                                 const float* __restrict__ res,
                                                 void* __restrict__ Yv, int M,
                                                 int out_f32) {
    __shared__ float As[16][72];
    __shared__ float Xs[16][72];
    const int n0 = blockIdx.x * 64;
    const int m0 = blockIdx.y * 64;
    const int b  = blockIdx.z;
    const u16* Xb = X + (size_t)b * CH * NSP;
    const int t  = threadIdx.x;
    const int tx = t & 15, ty = t >> 4;
    const int am = t >> 2, ak = (t & 3) * 4;   // A tile: 64 m x 16 k
    const int xk = t >> 4, xn4 = (t & 15) * 4; // X tile: 16 k x 64 n
    float acc[4][4] = {};
    for (int k0 = 0; k0 < CH; k0 += 16) {
        float4 av = *(const float4*)(A + (size_t)(m0 + am) * CH + k0 + ak);
        As[ak + 0][am] = av.x;
        As[ak + 1][am] = av.y;
        As[ak + 2][am] = av.z;
        As[ak + 3][am] = av.w;
        ushort4 xv = *(const ushort4*)(Xb + (size_t)(k0 + xk) * NSP + n0 + xn4);
        Xs[xk][xn4 + 0] = bf2f(xv.x);
        Xs[xk][xn4 + 1] = bf2f(xv.y);
        Xs[xk][xn4 + 2] = bf2f(xv.z);
        Xs[xk][xn4 + 3] = bf2f(xv.w);
        __syncthreads();
#pragma unroll
        for (int kk = 0; kk < 16; ++kk) {
            float4 a4 = *(const float4*)&As[kk][ty * 4];
            float4 x4 = *(const float4*)&Xs[kk][tx * 4];
            float aa[4] = {a4.x, a4.y, a4.z, a4.w};
            float xx[4] = {x4.x, x4.y, x4.z, x4.w};
#pragma unroll
            for (int i = 0; i < 4; ++i)
#pragma unroll
                for (int j = 0; j < 4; ++j) acc[i][j] += aa[i] * xx[j];
        }
        __syncthreads();
    }
#pragma unroll
    for (int i = 0; i < 4; ++i) {
        int r = m0 + ty * 4 + i;
        float bvv = bias[r];
        float v[4];
#pragma unroll
        for (int j = 0; j < 4; ++j) v[j] = acc[i][j] + bvv;
        if (out_f32) {
            const float* rp = res + (size_t)b * CH * NSP + (size_t)r * NSP + n0 + tx * 4;
            float4 rv = *(const float4*)rp;
            float4 ov;
            ov.x = v[0] + rv.x; ov.y = v[1] + rv.y;
            ov.z = v[2] + rv.z; ov.w = v[3] + rv.w;
            float* Yb = (float*)Yv + (size_t)b * M * NSP;
            *(float4*)(Yb + (size_t)r * NSP + n0 + tx * 4) = ov;
        } else {
            ushort4 ov; ov.x = f2bf(v[0]); ov.y = f2bf(v[1]);
            ov.z = f2bf(v[2]); ov.w = f2bf(v[3]);
            u16* Yb = (u16*)Yv + (size_t)b * M * NSP;
            *(ushort4*)(Yb + (size_t)r * NSP + n0 + tx * 4) = ov;
        }
    }
}

// --- transposed staging: 16 bf16 along the row dim -> dst[row0+j][col] ---
// Within each ds_write_u16 instruction the row is wave-uniform and col=lane,
// so the wave hits all 32 banks with same-dword merging: conflict-free.
__device__ __forceinline__ void wr_t16(u16 (*dst)[72], int row0, int col,
                                       const u16* __restrict__ src) {
    uint4 u0 = *(const uint4*)src;
    uint4 u1 = *(const uint4*)(src + 8);
    u32 w[8] = {u0.x, u0.y, u0.z, u0.w, u1.x, u1.y, u1.z, u1.w};
#pragma unroll
    for (int j = 0; j < 8; ++j) {
        dst[row0 + 2 * j][col]     = (u16)(w[j] & 0xFFFFu);
        dst[row0 + 2 * j + 1][col] = (u16)(w[j] >> 16);
    }
}

// ---------------- MFMA flash attention: one block per (b, h, 64-query tile) ----
// 4 waves x 16 queries. S^T = K^T Q (A=K frag from Ks[key][c], B=Q frag from
// Qs[q][c]); C/D layout puts a lane's 16 scores all on query q=lane&15 ->
// softmax = in-lane + shfl_xor(16,32). PV: O[c][q] = V P^T with A=Vs[c][key]
// (natural layout) and B=P from per-wave LDS round-trip Ps[q][key].
__global__ __launch_bounds__(256) void attn_mfma(const u16* __restrict__ qkv,
                                                 u16* __restrict__ ao) {
    __shared__ u16 Qs[64][72];
    __shared__ u16 Ks[64][72];
    __shared__ u16 Vs[64][72];
    __shared__ u16 Ps[4][16][72];
    const int n0 = blockIdx.x * 64;
    const int h  = blockIdx.y;
    const int b  = blockIdx.z;
    const u16* qb = qkv + ((size_t)b * 3 * CH + h * HDIM) * NSP;
    const u16* kb = qb + (size_t)CH * NSP;
    const u16* vb = kb + (size_t)CH * NSP;
    const int t    = threadIdx.x;
    const int wave = t >> 6, lane = t & 63;
    const int lq   = lane & 15, quad = lane >> 4;
    const int sc   = t & 63;        // staging channel (lane index -> bank spread)
    const int sg   = t >> 6;        // staging 16-col group (wave-uniform row)
    const int wq   = wave * 16;

    // stage Q transposed: Qs[q][c]
    wr_t16(Qs, sg * 16, sc, qb + (size_t)sc * NSP + n0 + sg * 16);

    float m_r = -1e30f, l_r = 0.f;
    f32x4 O[4] = {{0.f,0.f,0.f,0.f},{0.f,0.f,0.f,0.f},{0.f,0.f,0.f,0.f},{0.f,0.f,0.f,0.f}};

    for (int kt = 0; kt < 64; ++kt) {
        const int k0 = kt * 64;
        __syncthreads();   // prev iter's reads done (and Q visible on iter 0)
        // stage K transposed: Ks[key][c]
        wr_t16(Ks, sg * 16, sc, kb + (size_t)sc * NSP + k0 + sg * 16);
        // stage V natural: Vs[c][key]
        {
            const u16* vsrc = vb + (size_t)sc * NSP + k0 + sg * 16;
            *(uint4*)&Vs[sc][sg * 16]     = *(const uint4*)vsrc;
            *(uint4*)&Vs[sc][sg * 16 + 8] = *(const uint4*)(vsrc + 8);
        }
        __syncthreads();

        // S^T[key][q] for 64 keys x this wave's 16 q
        bf16x8 q0 = *(const bf16x8*)&Qs[wq + lq][quad * 8];
        bf16x8 q1 = *(const bf16x8*)&Qs[wq + lq][32 + quad * 8];
        f32x4 st[4];
#pragma unroll
        for (int mt = 0; mt < 4; ++mt) {
            bf16x8 a0 = *(const bf16x8*)&Ks[mt * 16 + lq][quad * 8];
            bf16x8 a1 = *(const bf16x8*)&Ks[mt * 16 + lq][32 + quad * 8];
            f32x4 acc = {0.f, 0.f, 0.f, 0.f};
            acc = __builtin_amdgcn_mfma_f32_16x16x32_bf16(a0, q0, acc, 0, 0, 0);
            acc = __builtin_amdgcn_mfma_f32_16x16x32_bf16(a1, q1, acc, 0, 0, 0);
            st[mt] = acc * 0.125f;   // scale = hd^-0.5
        }
        // online softmax over this lane's 16 scores (all same q) + cross-quad
        float mx = m_r;
#pragma unroll
        for (int mt = 0; mt < 4; ++mt)
#pragma unroll
            for (int r = 0; r < 4; ++r) mx = fmaxf(mx, st[mt][r]);
        mx = fmaxf(mx, __shfl_xor(mx, 16));
        mx = fmaxf(mx, __shfl_xor(mx, 32));
        float alpha = __expf(m_r - mx);
        m_r = mx;
        float sum = 0.f;
#pragma unroll
        for (int mt = 0; mt < 4; ++mt) {
            float p0 = __expf(st[mt][0] - mx);
            float p1 = __expf(st[mt][1] - mx);
            float p2 = __expf(st[mt][2] - mx);
            float p3 = __expf(st[mt][3] - mx);
            sum += p0 + p1 + p2 + p3;
            ushort4 pk;
            pk.x = f2bf(p0); pk.y = f2bf(p1); pk.z = f2bf(p2); pk.w = f2bf(p3);
            // keys mt*16 + quad*4 + {0..3} for row q=lq  (C-layout -> LDS)
            *(ushort4*)&Ps[wave][lq][mt * 16 + quad * 4] = pk;
        }
        sum += __shfl_xor(sum, 16);
        sum += __shfl_xor(sum, 32);
        l_r = l_r * alpha + sum;

        // PV: O[c][q] += V[c][key] * P^T[key][q]   (per-wave LDS ops are in-order)
        bf16x8 p0 = *(const bf16x8*)&Ps[wave][lq][quad * 8];
        bf16x8 p1 = *(const bf16x8*)&Ps[wave][lq][32 + quad * 8];
#pragma unroll
        for (int mtc = 0; mtc < 4; ++mtc) {
            O[mtc] *= alpha;
            bf16x8 v0 = *(const bf16x8*)&Vs[mtc * 16 + lq][quad * 8];
            bf16x8 v1 = *(const bf16x8*)&Vs[mtc * 16 + lq][32 + quad * 8];
            O[mtc] = __builtin_amdgcn_mfma_f32_16x16x32_bf16(v0, p0, O[mtc], 0, 0, 0);
            O[mtc] = __builtin_amdgcn_mfma_f32_16x16x32_bf16(v1, p1, O[mtc], 0, 0, 0);
        }
    }
    float linv = 1.f / l_r;
    u16* aob = ao + ((size_t)b * CH + h * HDIM) * NSP + n0 + wq + lq;
#pragma unroll
    for (int mtc = 0; mtc < 4; ++mtc)
#pragma unroll
        for (int r = 0; r < 4; ++r) {
            int c = mtc * 16 + quad * 4 + r;
            aob[(size_t)c * NSP] = f2bf(O[mtc][r] * linv);
        }
}

extern "C" void kernel_launch(void* const* d_in, const int* in_sizes, int n_in,
                              void* d_out, int out_size, void* d_ws, size_t ws_size,
                              hipStream_t stream) {
    const float* x      = (const float*)d_in[0];
    const float* norm_w = (const float*)d_in[1];
    const float* norm_b = (const float*)d_in[2];
    const float* qkv_w  = (const float*)d_in[3];
    const float* qkv_b  = (const float*)d_in[4];
    const float* proj_w = (const float*)d_in[5];
    const float* proj_b = (const float*)d_in[6];
    float* out = (float*)d_out;

    char* w = (char*)d_ws;
    float* stats = (float*)w;                                   // 128 B
    u16* xn  = (u16*)(w + 1024);                                // 4 MB bf16
    u16* qkv = (u16*)(w + 1024 + 4194304);                      // 12 MB bf16
    u16* ao  = (u16*)(w + 1024 + 4194304 + 12582912);           // 4 MB bf16

    gn_stats<<<dim3(NB * NG), 256, 0, stream>>>(x, stats);
    gn_apply<<<dim3(NB * CH), 256, 0, stream>>>(x, stats, norm_w, norm_b, xn);
    gemm_bias<<<dim3(NSP / 64, (3 * CH) / 64, NB), 256, 0, stream>>>(
        qkv_w, qkv_b, xn, nullptr, (void*)qkv, 3 * CH, 0);
    attn_mfma<<<dim3(NSP / 64, NHD, NB), 256, 0, stream>>>(qkv, ao);
    gemm_bias<<<dim3(NSP / 64, CH / 64, NB), 256, 0, stream>>>(
        proj_w, proj_b, ao, x, (void*)out, CH, 1);
}